// Round 10
// baseline (418.264 us; speedup 1.0000x reference)
//
#include <hip/hip_runtime.h>
#include <cstdint>

// Transformer block: LN1 -> {QK GEMM, V^T GEMM} -> flash attn (swapped-QK,
// in-register softmax in exp2 domain, permlane P re-layout) -> out-proj(+res)
// -> LN2 -> fc1(+GELU) -> fc2(+res). All matmuls bf16 MFMA, fp32 accum.
// R10: gemm8p (R7 4-phase/tile schedule, verified) + R9 L2-locality XCD
// partition (A-slice <= 2MB per XCD). attn: log2e folded into QK epilogue
// (Q cols scaled) -> exp2f softmax, max3-friendly max tree.

using short8 = __attribute__((ext_vector_type(8))) short;
using f32x4  = __attribute__((ext_vector_type(4))) float;
using f32x16 = __attribute__((ext_vector_type(16))) float;

#define EMBED  1024
#define HIDDEN 4096
#define SEQ    2048
#define NTOK   8192   // 4*2048
#define LOG2E  1.4426950408889634f

__device__ __forceinline__ ushort f2bf(float x) {
  union { float f; uint32_t u; } v; v.f = x;
  uint32_t r = v.u + 0x7fffu + ((v.u >> 16) & 1u);   // RNE
  return (ushort)(r >> 16);
}

__device__ __forceinline__ uint32_t pkbf(float lo, float hi) {
  uint32_t r;
  asm("v_cvt_pk_bf16_f32 %0, %1, %2" : "=v"(r) : "v"(lo), "v"(hi));
  return r;
}

__device__ __forceinline__ void gload16(const void* g, void* l) {
  __builtin_amdgcn_global_load_lds((__attribute__((address_space(1))) void*)(g),
                                   (__attribute__((address_space(3))) void*)(l), 16, 0, 0);
}

template<int N> __device__ __forceinline__ void vwait() {
  asm volatile("s_waitcnt vmcnt(%0)" :: "n"(N) : "memory");
}
__device__ __forceinline__ void lgkm0() {
  asm volatile("s_waitcnt lgkmcnt(0)" ::: "memory");
}
__device__ __forceinline__ void fence_bar() {
  asm volatile("" ::: "memory");
  __builtin_amdgcn_s_barrier();
  asm volatile("" ::: "memory");
}

__device__ __forceinline__ f32x4 mfma16(short8 a, short8 b, f32x4 c) {
  return __builtin_amdgcn_mfma_f32_16x16x32_bf16(a, b, c, 0, 0, 0);
}
__device__ __forceinline__ f32x16 mfma32(short8 a, short8 b, f32x16 c) {
  return __builtin_amdgcn_mfma_f32_32x32x16_bf16(a, b, c, 0, 0, 0);
}
__device__ __forceinline__ f32x16 zero16() {
  f32x16 z = {0.f,0.f,0.f,0.f,0.f,0.f,0.f,0.f,0.f,0.f,0.f,0.f,0.f,0.f,0.f,0.f};
  return z;
}

// ---------------- fp32 -> bf16 weight conversion ----------------
__global__ __launch_bounds__(256) void cvt_bf16_kernel(const float* __restrict__ in,
                                                       ushort* __restrict__ out, int n4) {
  int i = blockIdx.x * 256 + threadIdx.x;
  if (i < n4) {
    float4 v = reinterpret_cast<const float4*>(in)[i];
    ushort4 o; o.x = f2bf(v.x); o.y = f2bf(v.y); o.z = f2bf(v.z); o.w = f2bf(v.w);
    reinterpret_cast<ushort4*>(out)[i] = o;
  }
}

// ---------------- LayerNorm (fp32 in, bf16 out) ----------------
__global__ __launch_bounds__(256) void ln_kernel(const float* __restrict__ x,
                                                 const float* __restrict__ g,
                                                 const float* __restrict__ b,
                                                 ushort* __restrict__ out) {
  const int row = blockIdx.x, tid = threadIdx.x;
  const float4 xv = reinterpret_cast<const float4*>(x + (size_t)row * EMBED)[tid];
  float s  = xv.x + xv.y + xv.z + xv.w;
  float s2 = xv.x*xv.x + xv.y*xv.y + xv.z*xv.z + xv.w*xv.w;
  #pragma unroll
  for (int off = 32; off >= 1; off >>= 1) { s += __shfl_xor(s, off); s2 += __shfl_xor(s2, off); }
  __shared__ float ps[4], ps2[4];
  if ((tid & 63) == 0) { ps[tid >> 6] = s; ps2[tid >> 6] = s2; }
  __syncthreads();
  s  = ps[0] + ps[1] + ps[2] + ps[3];
  s2 = ps2[0] + ps2[1] + ps2[2] + ps2[3];
  const float mu  = s * (1.f / EMBED);
  const float var = s2 * (1.f / EMBED) - mu * mu;
  const float rs  = rsqrtf(var + 1e-5f);
  const float4 gv = reinterpret_cast<const float4*>(g)[tid];
  const float4 bv = reinterpret_cast<const float4*>(b)[tid];
  ushort4 o;
  o.x = f2bf((xv.x - mu) * rs * gv.x + bv.x);
  o.y = f2bf((xv.y - mu) * rs * gv.y + bv.y);
  o.z = f2bf((xv.z - mu) * rs * gv.z + bv.z);
  o.w = f2bf((xv.w - mu) * rs * gv.w + bv.w);
  reinterpret_cast<ushort4*>(out + (size_t)row * EMBED)[tid] = o;
}

// ---------------- bf16 GEMM: C[M,N] = A[M,K] * B[N,K]^T (+epilogue) ----------------
// 8-phase-class schedule (R7, verified): SQ 256x256 (8 waves 2Mx4N), SK 256x128
// (4Mx2N). Regions A0,A1[,B0][,B1] of [128][64] ush, chunk16 swizzle c^=(row&7).
// 4 phases/tile; regions staged for tile t+2 into the CURRENT buffer after
// their last reader phase; ONE counted vwait per tile; 2 barriers/phase.
// L2-locality partition (R9): XCD owns contiguous M-slice (or N-slice).
// EPI: 0 bf16 | 1 fp32+bias+res | 2 bf16 gelu(acc+bias) | 3 bf16, cols<1024 * log2e
template<int EPI, bool SQ>
__global__ __launch_bounds__(512) void gemm8p(const ushort* __restrict__ A,
                                              const ushort* __restrict__ B,
                                              const float* __restrict__ bias,
                                              const float* __restrict__ res,
                                              ushort* __restrict__ outb,
                                              float* __restrict__ outf,
                                              int M, int N, int K, int gx) {
  constexpr int BN   = SQ ? 256 : 128;
  constexpr int NH   = SQ ? 4 : 3;          // regions per buffer
  constexpr int HSZ  = 128 * 64;            // ushorts per region (16 KiB)
  constexpr int MPOS = SQ ? 8 : 4;          // 16-row m-frags per wave
  constexpr int MI   = SQ ? 4 : 2;          // m-frags per phase
  constexpr int NBH  = SQ ? 2 : 1;          // B regions
  constexpr int LPT  = SQ ? 8 : 6;          // gloads per tile per thread
  __shared__ ushort lds[2][NH * HSZ];

  const int nwg = gridDim.x;
  const int b0  = blockIdx.x;
  // L2-locality partition (XCD = blockIdx % 8)
  const int p = b0 & 7, li = b0 >> 3;
  int mt, nt;
  if ((gx & 7) == 0) {                      // partition M across XCDs
    const int g = gx >> 3;
    mt = p * g + (li % g);
    nt = li / g;
  } else {                                  // partition N across XCDs
    const int g = (nwg / gx) >> 3;
    nt = p * g + (li % g);
    mt = li / g;
  }
  const int m0 = mt * 256;
  const int n0 = nt * BN;

  const int tid = threadIdx.x, lane = tid & 63, wave = tid >> 6;
  const int l15 = lane & 15, l4 = lane >> 4;
  const int wm = SQ ? (wave >> 2) * 128 : (wave >> 1) * 64;
  const int wn = SQ ? (wave & 3) * 64 : (wave & 1) * 64;
  const int NT = K >> 6;                    // BK=64; NT even, >= 4

  const int aRegIdx = wave >> 2;                       // A region this wave reads
  const int lraB = SQ ? 0 : ((wave >> 1) & 1) * 64;    // local A row base
  const int bRegIdx = SQ ? (2 + ((wave & 3) >> 1)) : 2;
  const int lcB  = (wave & 1) * 64;                    // local B col base

  // fragment LDS offsets (ushort units) inside a region
  int aOff[2][MI][2], bOff[2][2][2];
  #pragma unroll
  for (int ms = 0; ms < 2; ++ms)
    #pragma unroll
    for (int i = 0; i < MI; ++i)
      #pragma unroll
      for (int ks = 0; ks < 2; ++ks) {
        const int lr = lraB + ms * (SQ ? 64 : 32) + i * 16 + l15;
        aOff[ms][i][ks] = lr * 64 + (((ks * 4 + l4) ^ (lr & 7)) * 8);
      }
  #pragma unroll
  for (int ns = 0; ns < 2; ++ns)
    #pragma unroll
    for (int j = 0; j < 2; ++j)
      #pragma unroll
      for (int ks = 0; ks < 2; ++ks) {
        const int c = lcB + ns * 32 + j * 16 + l15;
        bOff[ns][j][ks] = c * 64 + (((ks * 4 + l4) ^ (c & 7)) * 8);
      }

  // staging source pointers (pre-swizzled global source, linear LDS dest)
  const ushort* aP[2][2];
  const ushort* bP[NBH][2];
  #pragma unroll
  for (int h = 0; h < 2; ++h)
    #pragma unroll
    for (int rd = 0; rd < 2; ++rd) {
      const int slot = rd * 512 + tid, r = slot >> 3;
      aP[h][rd] = A + (size_t)(m0 + h * 128 + r) * K + (((slot & 7) ^ (r & 7)) * 8);
    }
  #pragma unroll
  for (int h = 0; h < NBH; ++h)
    #pragma unroll
    for (int rd = 0; rd < 2; ++rd) {
      const int slot = rd * 512 + tid, r = slot >> 3;
      bP[h][rd] = B + (size_t)(n0 + h * 128 + r) * K + (((slot & 7) ^ (r & 7)) * 8);
    }
  auto stA = [&](int par, int h, int rd) {
    gload16(aP[h][rd], &lds[par][h * HSZ + (rd * 512 + tid) * 8]);
  };
  auto stB = [&](int par, int h, int rd) {
    gload16(bP[h][rd], &lds[par][(2 + h) * HSZ + (rd * 512 + tid) * 8]);
  };
  auto advance = [&]() {
    #pragma unroll
    for (int h = 0; h < 2; ++h) { aP[h][0] += 64; aP[h][1] += 64; }
    #pragma unroll
    for (int h = 0; h < NBH; ++h) { bP[h][0] += 64; bP[h][1] += 64; }
  };

  // prologue: stage t0 -> buf0, t1 -> buf1 (B batch then A batch, LPT each)
  #pragma unroll
  for (int t = 0; t < 2; ++t) {
    #pragma unroll
    for (int h = 0; h < NBH; ++h) { stB(t, h, 0); stB(t, h, 1); }
    #pragma unroll
    for (int h = 0; h < 2; ++h) { stA(t, h, 0); stA(t, h, 1); }
    advance();
  }
  vwait<LPT>();                 // t0 resident; t1 in flight
  fence_bar();

  f32x4 acc[MPOS][4] = {};
  short8 af[MI][2], bf[2][2][2];

  auto RDA = [&](const ushort* LA, int ms) {
    #pragma unroll
    for (int i = 0; i < MI; ++i)
      #pragma unroll
      for (int ks = 0; ks < 2; ++ks)
        af[i][ks] = *reinterpret_cast<const short8*>(LA + aOff[ms][i][ks]);
  };
  auto RDB = [&](const ushort* LB, int ns) {
    #pragma unroll
    for (int j = 0; j < 2; ++j)
      #pragma unroll
      for (int ks = 0; ks < 2; ++ks)
        bf[ns][j][ks] = *reinterpret_cast<const short8*>(LB + bOff[ns][j][ks]);
  };
  auto MM = [&](int ms, int ns) {
    __builtin_amdgcn_s_setprio(1);
    #pragma unroll
    for (int ks = 0; ks < 2; ++ks)
      #pragma unroll
      for (int i = 0; i < MI; ++i)
        #pragma unroll
        for (int j = 0; j < 2; ++j)
          acc[ms * MI + i][ns * 2 + j] =
              mfma16(af[i][ks], bf[ns][j][ks], acc[ms * MI + i][ns * 2 + j]);
    __builtin_amdgcn_s_setprio(0);
  };

  // one BK=64 tile on buffer par; stages tile t+2 into the SAME buffer.
  auto TILE = [&](int par, bool st, int wmode) {
    const ushort* LA = &lds[par][aRegIdx * HSZ];
    const ushort* LB = &lds[par][bRegIdx * HSZ];
    // ph0
    RDA(LA, 0); RDB(LB, 0);
    fence_bar(); lgkm0();
    MM(0, 0);
    fence_bar();
    // ph1
    RDB(LB, 1);
    fence_bar(); lgkm0();
    MM(0, 1);
    fence_bar();
    // ph2 (B regions fully read by end of ph1 -> safe to overwrite)
    RDA(LA, 1);
    if (st) {
      #pragma unroll
      for (int h = 0; h < NBH; ++h) { stB(par, h, 0); stB(par, h, 1); }
    }
    fence_bar(); lgkm0();
    MM(1, 1);
    fence_bar();
    // ph3 (A regions fully read by end of ph2 -> safe to overwrite)
    if (st) {
      #pragma unroll
      for (int h = 0; h < 2; ++h) { stA(par, h, 0); stA(par, h, 1); }
    }
    MM(1, 0);
    if (wmode == 0)      vwait<LPT>();   // next tile's data resident
    else if (wmode == 1) vwait<0>();
    fence_bar();
    if (st) advance();
  };

  for (int u = 0; u < NT - 2; u += 2) {
    TILE(0, true, 0);
    TILE(1, (u + 1 < NT - 2), (u + 1 == NT - 2) ? 1 : 0);
  }
  TILE(0, false, 1);            // tile NT-2 (even parity; NT even)
  TILE(1, false, 2);            // tile NT-1

  // epilogue: 16x16 C-layout (row = +l4*4+r, col = +l15)
  #pragma unroll
  for (int mi = 0; mi < MPOS; ++mi)
    #pragma unroll
    for (int nj = 0; nj < 4; ++nj)
      #pragma unroll
      for (int r = 0; r < 4; ++r) {
        const int row = m0 + wm + mi * 16 + l4 * 4 + r;
        const int col = n0 + wn + nj * 16 + l15;
        const size_t idx = (size_t)row * N + col;
        float v = acc[mi][nj][r];
        if constexpr (EPI == 0) {
          outb[idx] = f2bf(v);
        } else if constexpr (EPI == 1) {
          outf[idx] = v + bias[col] + res[idx];
        } else if constexpr (EPI == 2) {
          v += bias[col];
          v = 0.5f * v * (1.f + erff(v * 0.70710678118654752f));
          outb[idx] = f2bf(v);
        } else {
          // EPI 3: scale Q columns (col < 1024) by log2e for exp2-domain softmax
          outb[idx] = f2bf((col < 1024) ? v * LOG2E : v);
        }
      }
}

// ---------------- flash attention, swapped-QK, exp2-domain softmax ----------------
// grid (B*H=64, SEQ/256=8), block 256 (4 waves). Wave: 64 q rows (2 sets of 32).
// qk: [8192][2048] bf16 (q*log2e at col h*64, k at col 1024+h*64).
// vt: [1024][8192] bf16. S' = S*log2e -> P = exp2(S'-m'). No 1/sqrt(d) scaling.
#define KVB 64
#define NTT (SEQ / KVB)

__global__ __launch_bounds__(256, 2) void attn_kernel(const ushort* __restrict__ qk,
                                                      const ushort* __restrict__ vt,
                                                      ushort* __restrict__ outp) {
  const int tid = threadIdx.x, lane = tid & 63, wq = tid >> 6;
  const int hi = lane >> 5, lo = lane & 31;
  const int b = blockIdx.x >> 4, h = blockIdx.x & 15;
  const int q0 = blockIdx.y * 256;

  __shared__ ushort sK[2][64 * 64];
  __shared__ ushort sVt[2][64 * 64];
  __shared__ float sBc[4][2][32];

  // Q fragments (B-operand): row q, k-chunk (hi*8) within kc*16
  short8 qf[2][4];
  #pragma unroll
  for (int s = 0; s < 2; ++s)
    #pragma unroll
    for (int kc = 0; kc < 4; ++kc)
      qf[s][kc] = *reinterpret_cast<const short8*>(
          qk + (size_t)(b * SEQ + q0 + wq * 64 + s * 32 + lo) * 2048 + h * 64 + kc * 16 + hi * 8);

  auto STAGE = [&](int bb, int kt) {
    #pragma unroll
    for (int i = 0; i < 2; ++i) {
      const int slot = i * 256 + tid;
      const int r = slot >> 3;
      const int c = (slot & 7) ^ (r & 7);           // inverse-swizzled source chunk
      gload16(qk + (size_t)(b * SEQ + kt + r) * 2048 + 1024 + h * 64 + c * 8,
              &sK[bb][(i * 256 + wq * 64) * 8]);
      gload16(vt + (size_t)(h * 64 + r) * 8192 + b * SEQ + kt + c * 8,
              &sVt[bb][(i * 256 + wq * 64) * 8]);
    }
  };

  f32x16 acc[2][2];
  #pragma unroll
  for (int s = 0; s < 2; ++s) { acc[s][0] = zero16(); acc[s][1] = zero16(); }
  float mst[2] = {-1e30f, -1e30f}, lst[2] = {0.f, 0.f};

  STAGE(0, 0);
  for (int t = 0; t < NTT; ++t) {
    const int cur = t & 1;
    __syncthreads();                       // staged buf[cur] ready; buf[cur^1] free
    if (t + 1 < NTT) STAGE(cur ^ 1, (t + 1) * KVB);

    // K fragments (A-operand): row kv, swizzled b128 reads
    short8 kf[2][4];
    #pragma unroll
    for (int kvb = 0; kvb < 2; ++kvb)
      #pragma unroll
      for (int kc = 0; kc < 4; ++kc) {
        const int row = kvb * 32 + lo, ch = kc * 2 + hi;
        kf[kvb][kc] = *reinterpret_cast<const short8*>(
            &sK[cur][(row * 8 + (ch ^ (row & 7))) * 8]);
      }

    short8 pa[2][4];
    #pragma unroll
    for (int s = 0; s < 2; ++s) {
      // S'^T = K * (Q*log2e)^T : lane holds q=lo, kv rows in regs (exp2 domain)
      f32x16 st[2];
      #pragma unroll
      for (int kvb = 0; kvb < 2; ++kvb) {
        f32x16 tq = zero16();
        tq = mfma32(kf[kvb][0], qf[s][0], tq);
        tq = mfma32(kf[kvb][1], qf[s][1], tq);
        tq = mfma32(kf[kvb][2], qf[s][2], tq);
        tq = mfma32(kf[kvb][3], qf[s][3], tq);
        st[kvb] = tq;
      }
      // row max: pairwise combine + max3-friendly triple chain
      f32x16 mm;
      #pragma unroll
      for (int r = 0; r < 16; ++r) mm[r] = fmaxf(st[0][r], st[1][r]);
      float pm = fmaxf(fmaxf(mm[0], mm[1]), mm[2]);
      pm = fmaxf(fmaxf(pm, mm[3]), mm[4]);
      pm = fmaxf(fmaxf(pm, mm[5]), mm[6]);
      pm = fmaxf(fmaxf(pm, mm[7]), mm[8]);
      pm = fmaxf(fmaxf(pm, mm[9]), mm[10]);
      pm = fmaxf(fmaxf(pm, mm[11]), mm[12]);
      pm = fmaxf(fmaxf(pm, mm[13]), mm[14]);
      pm = fmaxf(pm, mm[15]);
      pm = fmaxf(pm, __shfl_xor(pm, 32));
      // defer-max (exp2 domain): rescale only when max grew by > 8 nats = 11.54 bits
      if (__any(pm > mst[s] + 11.54f)) {
        const float mn = fmaxf(mst[s], pm);
        const float al = exp2f(mst[s] - mn);
        mst[s] = mn; lst[s] *= al;
        sBc[wq][s][lo] = al;
        asm volatile("s_waitcnt lgkmcnt(0)" ::: "memory");
        #pragma unroll
        for (int g = 0; g < 4; ++g) {
          const f32x4 a4 = *reinterpret_cast<const f32x4*>(&sBc[wq][s][g * 8 + hi * 4]);
          #pragma unroll
          for (int j = 0; j < 4; ++j) {
            acc[s][0][g * 4 + j] *= a4[j];
            acc[s][1][g * 4 + j] *= a4[j];
          }
        }
      }
      // P = exp2(S' - m'), row sum
      #pragma unroll
      for (int kvb = 0; kvb < 2; ++kvb)
        #pragma unroll
        for (int r = 0; r < 16; ++r)
          st[kvb][r] = exp2f(st[kvb][r] - mst[s]);
      {
        const f32x16 sv = st[0] + st[1];
        float sum = ((sv[0] + sv[1]) + (sv[2] + sv[3])) + ((sv[4] + sv[5]) + (sv[6] + sv[7]))
                  + ((sv[8] + sv[9]) + (sv[10] + sv[11])) + ((sv[12] + sv[13]) + (sv[14] + sv[15]));
        sum += __shfl_xor(sum, 32);
        lst[s] += sum;
      }
      // pack P -> bf16 A-fragments via cvt_pk + permlane32_swap
      #pragma unroll
      for (int kvb = 0; kvb < 2; ++kvb)
        #pragma unroll
        for (int f = 0; f < 2; ++f) {
          uint32_t wa = pkbf(st[kvb][f * 8 + 0], st[kvb][f * 8 + 1]);
          uint32_t wb = pkbf(st[kvb][f * 8 + 2], st[kvb][f * 8 + 3]);
          uint32_t wc = pkbf(st[kvb][f * 8 + 4], st[kvb][f * 8 + 5]);
          uint32_t wd = pkbf(st[kvb][f * 8 + 6], st[kvb][f * 8 + 7]);
          asm volatile("v_permlane32_swap_b32 %0, %1" : "+v"(wa), "+v"(wc));
          asm volatile("v_permlane32_swap_b32 %0, %1" : "+v"(wb), "+v"(wd));
          union { uint32_t w[4]; short8 v; } u;
          u.w[0] = wa; u.w[1] = wb; u.w[2] = wc; u.w[3] = wd;
          pa[s][kvb * 2 + f] = u.v;
        }
    }

    // O += P V  (B-operand = V^T rows d)
    #pragma unroll
    for (int db = 0; db < 2; ++db) {
      short8 vb[4];
      #pragma unroll
      for (int k4 = 0; k4 < 4; ++k4) {
        const int row = db * 32 + lo, ch = k4 * 2 + hi;
        vb[k4] = *reinterpret_cast<const short8*>(
            &sVt[cur][(row * 8 + (ch ^ (row & 7))) * 8]);
      }
      #pragma unroll
      for (int s = 0; s < 2; ++s) {
        acc[s][db] = mfma32(pa[s][0], vb[0], acc[s][db]);
        acc[s][db] = mfma32(pa[s][1], vb[1], acc[s][db]);
        acc[s][db] = mfma32(pa[s][2], vb[2], acc[s][db]);
        acc[s][db] = mfma32(pa[s][3], vb[3], acc[s][db]);
      }
    }
  }

  // epilogue: O /= l, write bf16 [8192][1024]
  #pragma unroll
  for (int s = 0; s < 2; ++s) sBc[wq][s][lo] = 1.f / lst[s];
  asm volatile("s_waitcnt lgkmcnt(0)" ::: "memory");
  #pragma unroll
  for (int s = 0; s < 2; ++s)
    #pragma unroll
    for (int g = 0; g < 4; ++g) {
      const f32x4 r4 = *reinterpret_cast<const f32x4*>(&sBc[wq][s][g * 8 + hi * 4]);
      #pragma unroll
      for (int j = 0; j < 4; ++j) {
        const int qrow = q0 + wq * 64 + s * 32 + g * 8 + hi * 4 + j;
        #pragma unroll
        for (int db = 0; db < 2; ++db)
          outp[(size_t)(b * SEQ + qrow) * EMBED + h * 64 + db * 32 + lo] =
              f2bf(acc[s][db][g * 4 + j] * r4[j]);
      }
    }
}

// ---------------- launch ----------------
extern "C" void kernel_launch(void* const* d_in, const int* in_sizes, int n_in,
                              void* d_out, int out_size, void* d_ws, size_t ws_size,
                              hipStream_t stream) {
  const float* x     = (const float*)d_in[0];
  const float* ln1_g = (const float*)d_in[1];
  const float* ln1_b = (const float*)d_in[2];
  const float* qkv_w = (const float*)d_in[3];
  const float* out_w = (const float*)d_in[4];
  const float* out_b = (const float*)d_in[5];
  const float* ln2_g = (const float*)d_in[6];
  const float* ln2_b = (const float*)d_in[7];
  const float* fc1_w = (const float*)d_in[8];
  const float* fc1_b = (const float*)d_in[9];
  const float* fc2_w = (const float*)d_in[10];
  const float* fc2_b = (const float*)d_in[11];
  float* out = (float*)d_out;
  char* ws = (char*)d_ws;

  // workspace layout (bytes)
  ushort* qkvw = (ushort*)(ws);                                   //  6291456
  ushort* outw = (ushort*)(ws + 6291456);                         //  2097152
  ushort* fc1w = (ushort*)(ws + 8388608);                         //  8388608
  ushort* fc2w = (ushort*)(ws + 16777216);                        //  8388608
  float*  x1   = (float*) (ws + 25165824);                        // 33554432
  ushort* hbuf = (ushort*)(ws + 58720256);                        // 16777216
  ushort* qkbuf= (ushort*)(ws + 75497472);                        // 33554432  [8192][2048]
  ushort* vtbuf= (ushort*)(ws + 109051904);                       // 16777216  [1024][8192]
  ushort* obuf = (ushort*)(ws + 125829120);                       // 16777216
  ushort* gbuf = qkbuf;  // gelu buf [8192][4096] reuses qk+vt+o regions (64 MiB)

  cvt_bf16_kernel<<<3072, 256, 0, stream>>>(qkv_w, qkvw, 3 * EMBED * EMBED / 4);
  cvt_bf16_kernel<<<1024, 256, 0, stream>>>(out_w, outw, EMBED * EMBED / 4);
  cvt_bf16_kernel<<<4096, 256, 0, stream>>>(fc1_w, fc1w, HIDDEN * EMBED / 4);
  cvt_bf16_kernel<<<4096, 256, 0, stream>>>(fc2_w, fc2w, EMBED * HIDDEN / 4);

  ln_kernel<<<NTOK, 256, 0, stream>>>(x, ln1_g, ln1_b, hbuf);
  // QK: [8192][2048] = hbuf * Wqk^T   (EPI3: Q cols scaled by log2e)
  gemm8p<3, true><<<256, 512, 0, stream>>>(hbuf, qkvw, nullptr, nullptr,
                                           qkbuf, nullptr, NTOK, 2 * EMBED, EMBED, 32);
  // V^T: [1024][8192] = Wv * hbuf^T   (N-partitioned)
  gemm8p<0, false><<<256, 512, 0, stream>>>(qkvw + 2048 * 1024, hbuf, nullptr, nullptr,
                                            vtbuf, nullptr, EMBED, NTOK, EMBED, 4);
  attn_kernel<<<dim3(64, 8), 256, 0, stream>>>(qkbuf, vtbuf, obuf);
  // out-proj
  gemm8p<1, false><<<256, 512, 0, stream>>>(obuf, outw, out_b, x,
                                            nullptr, x1, NTOK, EMBED, EMBED, 32);
  ln_kernel<<<NTOK, 256, 0, stream>>>(x1, ln2_g, ln2_b, hbuf);
  // fc1
  gemm8p<2, true><<<512, 512, 0, stream>>>(hbuf, fc1w, fc1_b, nullptr,
                                           gbuf, nullptr, NTOK, HIDDEN, EMBED, 32);
  // fc2
  gemm8p<1, false><<<256, 512, 0, stream>>>(gbuf, fc2w, fc2_b, x1,
                                            nullptr, out, NTOK, EMBED, HIDDEN, 32);
}

// Round 11
// 387.563 us; speedup vs baseline: 1.0792x; 1.0792x over previous
//
#include <hip/hip_runtime.h>
#include <cstdint>

// Transformer block: LN1 -> {QK GEMM, V^T GEMM} -> flash attn (swapped-QK,
// in-register softmax, permlane P re-layout) -> out-proj(+res) -> LN2
// -> fc1(+GELU) -> fc2(+res). All matmuls bf16 MFMA, fp32 accum.
// R11: GEMM = gemm8p (R7 schedule + R9 L2-locality partition, verified).
// attn: R9 math (__expf, unscaled Q) restructured to 8 waves x 32 q-rows
// (512 threads) -> 16 waves/CU to fill latency stalls (was 8 waves/CU).

using short8 = __attribute__((ext_vector_type(8))) short;
using f32x4  = __attribute__((ext_vector_type(4))) float;
using f32x16 = __attribute__((ext_vector_type(16))) float;

#define EMBED  1024
#define HIDDEN 4096
#define SEQ    2048
#define NTOK   8192   // 4*2048

__device__ __forceinline__ ushort f2bf(float x) {
  union { float f; uint32_t u; } v; v.f = x;
  uint32_t r = v.u + 0x7fffu + ((v.u >> 16) & 1u);   // RNE
  return (ushort)(r >> 16);
}

__device__ __forceinline__ uint32_t pkbf(float lo, float hi) {
  uint32_t r;
  asm("v_cvt_pk_bf16_f32 %0, %1, %2" : "=v"(r) : "v"(lo), "v"(hi));
  return r;
}

__device__ __forceinline__ void gload16(const void* g, void* l) {
  __builtin_amdgcn_global_load_lds((__attribute__((address_space(1))) void*)(g),
                                   (__attribute__((address_space(3))) void*)(l), 16, 0, 0);
}

template<int N> __device__ __forceinline__ void vwait() {
  asm volatile("s_waitcnt vmcnt(%0)" :: "n"(N) : "memory");
}
__device__ __forceinline__ void lgkm0() {
  asm volatile("s_waitcnt lgkmcnt(0)" ::: "memory");
}
__device__ __forceinline__ void fence_bar() {
  asm volatile("" ::: "memory");
  __builtin_amdgcn_s_barrier();
  asm volatile("" ::: "memory");
}

__device__ __forceinline__ f32x4 mfma16(short8 a, short8 b, f32x4 c) {
  return __builtin_amdgcn_mfma_f32_16x16x32_bf16(a, b, c, 0, 0, 0);
}
__device__ __forceinline__ f32x16 mfma32(short8 a, short8 b, f32x16 c) {
  return __builtin_amdgcn_mfma_f32_32x32x16_bf16(a, b, c, 0, 0, 0);
}
__device__ __forceinline__ f32x16 zero16() {
  f32x16 z = {0.f,0.f,0.f,0.f,0.f,0.f,0.f,0.f,0.f,0.f,0.f,0.f,0.f,0.f,0.f,0.f};
  return z;
}

// ---------------- fp32 -> bf16 weight conversion ----------------
__global__ __launch_bounds__(256) void cvt_bf16_kernel(const float* __restrict__ in,
                                                       ushort* __restrict__ out, int n4) {
  int i = blockIdx.x * 256 + threadIdx.x;
  if (i < n4) {
    float4 v = reinterpret_cast<const float4*>(in)[i];
    ushort4 o; o.x = f2bf(v.x); o.y = f2bf(v.y); o.z = f2bf(v.z); o.w = f2bf(v.w);
    reinterpret_cast<ushort4*>(out)[i] = o;
  }
}

// ---------------- LayerNorm (fp32 in, bf16 out) ----------------
__global__ __launch_bounds__(256) void ln_kernel(const float* __restrict__ x,
                                                 const float* __restrict__ g,
                                                 const float* __restrict__ b,
                                                 ushort* __restrict__ out) {
  const int row = blockIdx.x, tid = threadIdx.x;
  const float4 xv = reinterpret_cast<const float4*>(x + (size_t)row * EMBED)[tid];
  float s  = xv.x + xv.y + xv.z + xv.w;
  float s2 = xv.x*xv.x + xv.y*xv.y + xv.z*xv.z + xv.w*xv.w;
  #pragma unroll
  for (int off = 32; off >= 1; off >>= 1) { s += __shfl_xor(s, off); s2 += __shfl_xor(s2, off); }
  __shared__ float ps[4], ps2[4];
  if ((tid & 63) == 0) { ps[tid >> 6] = s; ps2[tid >> 6] = s2; }
  __syncthreads();
  s  = ps[0] + ps[1] + ps[2] + ps[3];
  s2 = ps2[0] + ps2[1] + ps2[2] + ps2[3];
  const float mu  = s * (1.f / EMBED);
  const float var = s2 * (1.f / EMBED) - mu * mu;
  const float rs  = rsqrtf(var + 1e-5f);
  const float4 gv = reinterpret_cast<const float4*>(g)[tid];
  const float4 bv = reinterpret_cast<const float4*>(b)[tid];
  ushort4 o;
  o.x = f2bf((xv.x - mu) * rs * gv.x + bv.x);
  o.y = f2bf((xv.y - mu) * rs * gv.y + bv.y);
  o.z = f2bf((xv.z - mu) * rs * gv.z + bv.z);
  o.w = f2bf((xv.w - mu) * rs * gv.w + bv.w);
  reinterpret_cast<ushort4*>(out + (size_t)row * EMBED)[tid] = o;
}

// ---------------- bf16 GEMM: C[M,N] = A[M,K] * B[N,K]^T (+epilogue) ----------------
// 8-phase-class schedule (R7, verified): SQ 256x256 (8 waves 2Mx4N), SK 256x128
// (4Mx2N). Regions A0,A1[,B0][,B1] of [128][64] ush, chunk16 swizzle c^=(row&7).
// 4 phases/tile; regions staged for tile t+2 into the CURRENT buffer after
// their last reader phase; ONE counted vwait per tile; 2 barriers/phase.
// L2-locality partition (R9): XCD owns contiguous M-slice (or N-slice).
template<int EPI, bool SQ>
__global__ __launch_bounds__(512) void gemm8p(const ushort* __restrict__ A,
                                              const ushort* __restrict__ B,
                                              const float* __restrict__ bias,
                                              const float* __restrict__ res,
                                              ushort* __restrict__ outb,
                                              float* __restrict__ outf,
                                              int M, int N, int K, int gx) {
  constexpr int BN   = SQ ? 256 : 128;
  constexpr int NH   = SQ ? 4 : 3;          // regions per buffer
  constexpr int HSZ  = 128 * 64;            // ushorts per region (16 KiB)
  constexpr int MPOS = SQ ? 8 : 4;          // 16-row m-frags per wave
  constexpr int MI   = SQ ? 4 : 2;          // m-frags per phase
  constexpr int NBH  = SQ ? 2 : 1;          // B regions
  constexpr int LPT  = SQ ? 8 : 6;          // gloads per tile per thread
  __shared__ ushort lds[2][NH * HSZ];

  const int nwg = gridDim.x;
  const int b0  = blockIdx.x;
  // L2-locality partition (XCD = blockIdx % 8)
  const int p = b0 & 7, li = b0 >> 3;
  int mt, nt;
  if ((gx & 7) == 0) {                      // partition M across XCDs
    const int g = gx >> 3;
    mt = p * g + (li % g);
    nt = li / g;
  } else {                                  // partition N across XCDs
    const int g = (nwg / gx) >> 3;
    nt = p * g + (li % g);
    mt = li / g;
  }
  const int m0 = mt * 256;
  const int n0 = nt * BN;

  const int tid = threadIdx.x, lane = tid & 63, wave = tid >> 6;
  const int l15 = lane & 15, l4 = lane >> 4;
  const int wm = SQ ? (wave >> 2) * 128 : (wave >> 1) * 64;
  const int wn = SQ ? (wave & 3) * 64 : (wave & 1) * 64;
  const int NT = K >> 6;                    // BK=64; NT even, >= 4

  const int aRegIdx = wave >> 2;                       // A region this wave reads
  const int lraB = SQ ? 0 : ((wave >> 1) & 1) * 64;    // local A row base
  const int bRegIdx = SQ ? (2 + ((wave & 3) >> 1)) : 2;
  const int lcB  = (wave & 1) * 64;                    // local B col base

  // fragment LDS offsets (ushort units) inside a region
  int aOff[2][MI][2], bOff[2][2][2];
  #pragma unroll
  for (int ms = 0; ms < 2; ++ms)
    #pragma unroll
    for (int i = 0; i < MI; ++i)
      #pragma unroll
      for (int ks = 0; ks < 2; ++ks) {
        const int lr = lraB + ms * (SQ ? 64 : 32) + i * 16 + l15;
        aOff[ms][i][ks] = lr * 64 + (((ks * 4 + l4) ^ (lr & 7)) * 8);
      }
  #pragma unroll
  for (int ns = 0; ns < 2; ++ns)
    #pragma unroll
    for (int j = 0; j < 2; ++j)
      #pragma unroll
      for (int ks = 0; ks < 2; ++ks) {
        const int c = lcB + ns * 32 + j * 16 + l15;
        bOff[ns][j][ks] = c * 64 + (((ks * 4 + l4) ^ (c & 7)) * 8);
      }

  // staging source pointers (pre-swizzled global source, linear LDS dest)
  const ushort* aP[2][2];
  const ushort* bP[NBH][2];
  #pragma unroll
  for (int h = 0; h < 2; ++h)
    #pragma unroll
    for (int rd = 0; rd < 2; ++rd) {
      const int slot = rd * 512 + tid, r = slot >> 3;
      aP[h][rd] = A + (size_t)(m0 + h * 128 + r) * K + (((slot & 7) ^ (r & 7)) * 8);
    }
  #pragma unroll
  for (int h = 0; h < NBH; ++h)
    #pragma unroll
    for (int rd = 0; rd < 2; ++rd) {
      const int slot = rd * 512 + tid, r = slot >> 3;
      bP[h][rd] = B + (size_t)(n0 + h * 128 + r) * K + (((slot & 7) ^ (r & 7)) * 8);
    }
  auto stA = [&](int par, int h, int rd) {
    gload16(aP[h][rd], &lds[par][h * HSZ + (rd * 512 + tid) * 8]);
  };
  auto stB = [&](int par, int h, int rd) {
    gload16(bP[h][rd], &lds[par][(2 + h) * HSZ + (rd * 512 + tid) * 8]);
  };
  auto advance = [&]() {
    #pragma unroll
    for (int h = 0; h < 2; ++h) { aP[h][0] += 64; aP[h][1] += 64; }
    #pragma unroll
    for (int h = 0; h < NBH; ++h) { bP[h][0] += 64; bP[h][1] += 64; }
  };

  // prologue: stage t0 -> buf0, t1 -> buf1 (B batch then A batch, LPT each)
  #pragma unroll
  for (int t = 0; t < 2; ++t) {
    #pragma unroll
    for (int h = 0; h < NBH; ++h) { stB(t, h, 0); stB(t, h, 1); }
    #pragma unroll
    for (int h = 0; h < 2; ++h) { stA(t, h, 0); stA(t, h, 1); }
    advance();
  }
  vwait<LPT>();                 // t0 resident; t1 in flight
  fence_bar();

  f32x4 acc[MPOS][4] = {};
  short8 af[MI][2], bf[2][2][2];

  auto RDA = [&](const ushort* LA, int ms) {
    #pragma unroll
    for (int i = 0; i < MI; ++i)
      #pragma unroll
      for (int ks = 0; ks < 2; ++ks)
        af[i][ks] = *reinterpret_cast<const short8*>(LA + aOff[ms][i][ks]);
  };
  auto RDB = [&](const ushort* LB, int ns) {
    #pragma unroll
    for (int j = 0; j < 2; ++j)
      #pragma unroll
      for (int ks = 0; ks < 2; ++ks)
        bf[ns][j][ks] = *reinterpret_cast<const short8*>(LB + bOff[ns][j][ks]);
  };
  auto MM = [&](int ms, int ns) {
    __builtin_amdgcn_s_setprio(1);
    #pragma unroll
    for (int ks = 0; ks < 2; ++ks)
      #pragma unroll
      for (int i = 0; i < MI; ++i)
        #pragma unroll
        for (int j = 0; j < 2; ++j)
          acc[ms * MI + i][ns * 2 + j] =
              mfma16(af[i][ks], bf[ns][j][ks], acc[ms * MI + i][ns * 2 + j]);
    __builtin_amdgcn_s_setprio(0);
  };

  // one BK=64 tile on buffer par; stages tile t+2 into the SAME buffer.
  auto TILE = [&](int par, bool st, int wmode) {
    const ushort* LA = &lds[par][aRegIdx * HSZ];
    const ushort* LB = &lds[par][bRegIdx * HSZ];
    // ph0
    RDA(LA, 0); RDB(LB, 0);
    fence_bar(); lgkm0();
    MM(0, 0);
    fence_bar();
    // ph1
    RDB(LB, 1);
    fence_bar(); lgkm0();
    MM(0, 1);
    fence_bar();
    // ph2 (B regions fully read by end of ph1 -> safe to overwrite)
    RDA(LA, 1);
    if (st) {
      #pragma unroll
      for (int h = 0; h < NBH; ++h) { stB(par, h, 0); stB(par, h, 1); }
    }
    fence_bar(); lgkm0();
    MM(1, 1);
    fence_bar();
    // ph3 (A regions fully read by end of ph2 -> safe to overwrite)
    if (st) {
      #pragma unroll
      for (int h = 0; h < 2; ++h) { stA(par, h, 0); stA(par, h, 1); }
    }
    MM(1, 0);
    if (wmode == 0)      vwait<LPT>();   // next tile's data resident
    else if (wmode == 1) vwait<0>();
    fence_bar();
    if (st) advance();
  };

  for (int u = 0; u < NT - 2; u += 2) {
    TILE(0, true, 0);
    TILE(1, (u + 1 < NT - 2), (u + 1 == NT - 2) ? 1 : 0);
  }
  TILE(0, false, 1);            // tile NT-2 (even parity; NT even)
  TILE(1, false, 2);            // tile NT-1

  // epilogue: 16x16 C-layout (row = +l4*4+r, col = +l15)
  #pragma unroll
  for (int mi = 0; mi < MPOS; ++mi)
    #pragma unroll
    for (int nj = 0; nj < 4; ++nj)
      #pragma unroll
      for (int r = 0; r < 4; ++r) {
        const int row = m0 + wm + mi * 16 + l4 * 4 + r;
        const int col = n0 + wn + nj * 16 + l15;
        const size_t idx = (size_t)row * N + col;
        float v = acc[mi][nj][r];
        if constexpr (EPI == 0) {
          outb[idx] = f2bf(v);
        } else if constexpr (EPI == 1) {
          outf[idx] = v + bias[col] + res[idx];
        } else {
          v += bias[col];
          v = 0.5f * v * (1.f + erff(v * 0.70710678118654752f));
          outb[idx] = f2bf(v);
        }
      }
}

// ---------------- flash attention, swapped-QK in-register softmax ----------------
// grid (B*H=64, SEQ/256=8), block 512 (8 waves). Wave: 32 q rows.
// qk: [8192][2048] bf16 (q at col h*64, k at col 1024+h*64). vt: [1024][8192] bf16.
// No 1/sqrt(d) scaling (per reference). R9 math; 2x TLP vs R9 (16 waves/CU).
#define KVB 64
#define NTT (SEQ / KVB)

__global__ __launch_bounds__(512, 4) void attn_kernel(const ushort* __restrict__ qk,
                                                      const ushort* __restrict__ vt,
                                                      ushort* __restrict__ outp) {
  const int tid = threadIdx.x, lane = tid & 63, wq = tid >> 6;   // wq 0..7
  const int hi = lane >> 5, lo = lane & 31;
  const int b = blockIdx.x >> 4, h = blockIdx.x & 15;
  const int q0 = blockIdx.y * 256;

  __shared__ ushort sK[2][64 * 64];
  __shared__ ushort sVt[2][64 * 64];
  __shared__ float sBc[8][32];

  // Q fragments (B-operand): wave covers q rows q0 + wq*32 .. +31 (lane q = lo)
  short8 qf[4];
  #pragma unroll
  for (int kc = 0; kc < 4; ++kc)
    qf[kc] = *reinterpret_cast<const short8*>(
        qk + (size_t)(b * SEQ + q0 + wq * 32 + lo) * 2048 + h * 64 + kc * 16 + hi * 8);

  auto STAGE = [&](int bb, int kt) {
    const int r = tid >> 3;
    const int c = (tid & 7) ^ (r & 7);            // inverse-swizzled source chunk
    gload16(qk + (size_t)(b * SEQ + kt + r) * 2048 + 1024 + h * 64 + c * 8,
            &sK[bb][wq * 64 * 8]);                // wave-uniform dest + lane*16B
    gload16(vt + (size_t)(h * 64 + r) * 8192 + b * SEQ + kt + c * 8,
            &sVt[bb][wq * 64 * 8]);
  };

  f32x16 acc[2];
  acc[0] = zero16(); acc[1] = zero16();
  float mst = -1e30f, lst = 0.f;

  STAGE(0, 0);
  for (int t = 0; t < NTT; ++t) {
    const int cur = t & 1;
    __syncthreads();                       // staged buf[cur] ready; buf[cur^1] free
    if (t + 1 < NTT) STAGE(cur ^ 1, (t + 1) * KVB);

    // K fragments (A-operand): row kv, swizzled b128 reads
    short8 kf[2][4];
    #pragma unroll
    for (int kvb = 0; kvb < 2; ++kvb)
      #pragma unroll
      for (int kc = 0; kc < 4; ++kc) {
        const int row = kvb * 32 + lo, ch = kc * 2 + hi;
        kf[kvb][kc] = *reinterpret_cast<const short8*>(
            &sK[cur][(row * 8 + (ch ^ (row & 7))) * 8]);
      }

    // S^T = K * Q^T : lane holds q=lo, kv rows in regs
    f32x16 st[2];
    #pragma unroll
    for (int kvb = 0; kvb < 2; ++kvb) {
      f32x16 tq = zero16();
      tq = mfma32(kf[kvb][0], qf[0], tq);
      tq = mfma32(kf[kvb][1], qf[1], tq);
      tq = mfma32(kf[kvb][2], qf[2], tq);
      tq = mfma32(kf[kvb][3], qf[3], tq);
      st[kvb] = tq;
    }
    // row max: in-register tree + one cross-half swap
    float pm = fmaxf(st[0][0], st[0][1]);
    #pragma unroll
    for (int r = 2; r < 16; ++r) pm = fmaxf(pm, st[0][r]);
    #pragma unroll
    for (int r = 0; r < 16; ++r) pm = fmaxf(pm, st[1][r]);
    pm = fmaxf(pm, __shfl_xor(pm, 32));
    // defer-max: rescale only when max grew by > 8
    if (__any(pm > mst + 8.f)) {
      const float mn = fmaxf(mst, pm);
      const float al = __expf(mst - mn);
      mst = mn; lst *= al;
      sBc[wq][lo] = al;
      lgkm0();
      #pragma unroll
      for (int g = 0; g < 4; ++g) {
        const f32x4 a4 = *reinterpret_cast<const f32x4*>(&sBc[wq][g * 8 + hi * 4]);
        #pragma unroll
        for (int j = 0; j < 4; ++j) {
          acc[0][g * 4 + j] *= a4[j];
          acc[1][g * 4 + j] *= a4[j];
        }
      }
    }
    // P = exp(S - m), row sum
    #pragma unroll
    for (int kvb = 0; kvb < 2; ++kvb)
      #pragma unroll
      for (int r = 0; r < 16; ++r)
        st[kvb][r] = __expf(st[kvb][r] - mst);
    {
      const f32x16 sv = st[0] + st[1];
      float sum = ((sv[0] + sv[1]) + (sv[2] + sv[3])) + ((sv[4] + sv[5]) + (sv[6] + sv[7]))
                + ((sv[8] + sv[9]) + (sv[10] + sv[11])) + ((sv[12] + sv[13]) + (sv[14] + sv[15]));
      sum += __shfl_xor(sum, 32);
      lst += sum;
    }
    // pack P -> bf16 A-fragments via cvt_pk + permlane32_swap
    short8 pa[4];
    #pragma unroll
    for (int kvb = 0; kvb < 2; ++kvb)
      #pragma unroll
      for (int f = 0; f < 2; ++f) {
        uint32_t wa = pkbf(st[kvb][f * 8 + 0], st[kvb][f * 8 + 1]);
        uint32_t wb = pkbf(st[kvb][f * 8 + 2], st[kvb][f * 8 + 3]);
        uint32_t wc = pkbf(st[kvb][f * 8 + 4], st[kvb][f * 8 + 5]);
        uint32_t wd = pkbf(st[kvb][f * 8 + 6], st[kvb][f * 8 + 7]);
        asm volatile("v_permlane32_swap_b32 %0, %1" : "+v"(wa), "+v"(wc));
        asm volatile("v_permlane32_swap_b32 %0, %1" : "+v"(wb), "+v"(wd));
        union { uint32_t w[4]; short8 v; } u;
        u.w[0] = wa; u.w[1] = wb; u.w[2] = wc; u.w[3] = wd;
        pa[kvb * 2 + f] = u.v;
      }

    // O += P V  (B-operand = V^T rows d)
    #pragma unroll
    for (int db = 0; db < 2; ++db) {
      short8 vb[4];
      #pragma unroll
      for (int k4 = 0; k4 < 4; ++k4) {
        const int row = db * 32 + lo, ch = k4 * 2 + hi;
        vb[k4] = *reinterpret_cast<const short8*>(
            &sVt[cur][(row * 8 + (ch ^ (row & 7))) * 8]);
      }
      acc[db] = mfma32(pa[0], vb[0], acc[db]);
      acc[db] = mfma32(pa[1], vb[1], acc[db]);
      acc[db] = mfma32(pa[2], vb[2], acc[db]);
      acc[db] = mfma32(pa[3], vb[3], acc[db]);
    }
  }

  // epilogue: O /= l, write bf16 [8192][1024]
  sBc[wq][lo] = 1.f / lst;
  lgkm0();
  #pragma unroll
  for (int g = 0; g < 4; ++g) {
    const f32x4 r4 = *reinterpret_cast<const f32x4*>(&sBc[wq][g * 8 + hi * 4]);
    #pragma unroll
    for (int j = 0; j < 4; ++j) {
      const int qrow = q0 + wq * 32 + g * 8 + hi * 4 + j;
      #pragma unroll
      for (int db = 0; db < 2; ++db)
        outp[(size_t)(b * SEQ + qrow) * EMBED + h * 64 + db * 32 + lo] =
            f2bf(acc[db][g * 4 + j] * r4[j]);
    }
  }
}

// ---------------- launch ----------------
extern "C" void kernel_launch(void* const* d_in, const int* in_sizes, int n_in,
                              void* d_out, int out_size, void* d_ws, size_t ws_size,
                              hipStream_t stream) {
  const float* x     = (const float*)d_in[0];
  const float* ln1_g = (const float*)d_in[1];
  const float* ln1_b = (const float*)d_in[2];
  const float* qkv_w = (const float*)d_in[3];
  const float* out_w = (const float*)d_in[4];
  const float* out_b = (const float*)d_in[5];
  const float* ln2_g = (const float*)d_in[6];
  const float* ln2_b = (const float*)d_in[7];
  const float* fc1_w = (const float*)d_in[8];
  const float* fc1_b = (const float*)d_in[9];
  const float* fc2_w = (const float*)d_in[10];
  const float* fc2_b = (const float*)d_in[11];
  float* out = (float*)d_out;
  char* ws = (char*)d_ws;

  // workspace layout (bytes)
  ushort* qkvw = (ushort*)(ws);                                   //  6291456
  ushort* outw = (ushort*)(ws + 6291456);                         //  2097152
  ushort* fc1w = (ushort*)(ws + 8388608);                         //  8388608
  ushort* fc2w = (ushort*)(ws + 16777216);                        //  8388608
  float*  x1   = (float*) (ws + 25165824);                        // 33554432
  ushort* hbuf = (ushort*)(ws + 58720256);                        // 16777216
  ushort* qkbuf= (ushort*)(ws + 75497472);                        // 33554432  [8192][2048]
  ushort* vtbuf= (ushort*)(ws + 109051904);                       // 16777216  [1024][8192]
  ushort* obuf = (ushort*)(ws + 125829120);                       // 16777216
  ushort* gbuf = qkbuf;  // gelu buf [8192][4096] reuses qk+vt+o regions (64 MiB)

  cvt_bf16_kernel<<<3072, 256, 0, stream>>>(qkv_w, qkvw, 3 * EMBED * EMBED / 4);
  cvt_bf16_kernel<<<1024, 256, 0, stream>>>(out_w, outw, EMBED * EMBED / 4);
  cvt_bf16_kernel<<<4096, 256, 0, stream>>>(fc1_w, fc1w, HIDDEN * EMBED / 4);
  cvt_bf16_kernel<<<4096, 256, 0, stream>>>(fc2_w, fc2w, EMBED * HIDDEN / 4);

  ln_kernel<<<NTOK, 256, 0, stream>>>(x, ln1_g, ln1_b, hbuf);
  // QK: [8192][2048] = hbuf * Wqk^T
  gemm8p<0, true><<<256, 512, 0, stream>>>(hbuf, qkvw, nullptr, nullptr,
                                           qkbuf, nullptr, NTOK, 2 * EMBED, EMBED, 32);
  // V^T: [1024][8192] = Wv * hbuf^T   (N-partitioned)
  gemm8p<0, false><<<256, 512, 0, stream>>>(qkvw + 2048 * 1024, hbuf, nullptr, nullptr,
                                            vtbuf, nullptr, EMBED, NTOK, EMBED, 4);
  attn_kernel<<<dim3(64, 8), 512, 0, stream>>>(qkbuf, vtbuf, obuf);
  // out-proj
  gemm8p<1, false><<<256, 512, 0, stream>>>(obuf, outw, out_b, x,
                                            nullptr, x1, NTOK, EMBED, EMBED, 32);
  ln_kernel<<<NTOK, 256, 0, stream>>>(x1, ln2_g, ln2_b, hbuf);
  // fc1
  gemm8p<2, true><<<512, 512, 0, stream>>>(hbuf, fc1w, fc1_b, nullptr,
                                           gbuf, nullptr, NTOK, HIDDEN, EMBED, 32);
  // fc2
  gemm8p<1, false><<<256, 512, 0, stream>>>(gbuf, fc2w, fc2_b, x1,
                                            nullptr, out, NTOK, EMBED, HIDDEN, 32);
}

// Round 12
// 384.522 us; speedup vs baseline: 1.0877x; 1.0079x over previous
//
#include <hip/hip_runtime.h>
#include <cstdint>

// Transformer block: LN1 -> {QK GEMM, V^T GEMM} -> flash attn (swapped-QK,
// in-register softmax, permlane P re-layout) -> out-proj(+res) -> LN2
// -> fc1(+GELU) -> fc2(+res). All matmuls bf16 MFMA, fp32 accum.
// R12 consolidation: GEMM = R9's gemm256 (quad-buffered BK=32, counted vmcnt,
// L2-locality XCD partition) — best-measured GEMM config. attn = R11's 8-wave
// 512-thread structure (16 waves/CU) with R9 softmax math.

using short8 = __attribute__((ext_vector_type(8))) short;
using f32x4  = __attribute__((ext_vector_type(4))) float;
using f32x16 = __attribute__((ext_vector_type(16))) float;

#define EMBED  1024
#define HIDDEN 4096
#define SEQ    2048
#define NTOK   8192   // 4*2048

__device__ __forceinline__ ushort f2bf(float x) {
  union { float f; uint32_t u; } v; v.f = x;
  uint32_t r = v.u + 0x7fffu + ((v.u >> 16) & 1u);   // RNE
  return (ushort)(r >> 16);
}

__device__ __forceinline__ uint32_t pkbf(float lo, float hi) {
  uint32_t r;
  asm("v_cvt_pk_bf16_f32 %0, %1, %2" : "=v"(r) : "v"(lo), "v"(hi));
  return r;
}

__device__ __forceinline__ void gload16(const void* g, void* l) {
  __builtin_amdgcn_global_load_lds((__attribute__((address_space(1))) void*)(g),
                                   (__attribute__((address_space(3))) void*)(l), 16, 0, 0);
}

template<int N> __device__ __forceinline__ void vwait() {
  asm volatile("s_waitcnt vmcnt(%0)" :: "n"(N) : "memory");
}
__device__ __forceinline__ void lgkm0() {
  asm volatile("s_waitcnt lgkmcnt(0)" ::: "memory");
}
__device__ __forceinline__ void fence_bar() {
  asm volatile("" ::: "memory");
  __builtin_amdgcn_s_barrier();
  asm volatile("" ::: "memory");
}

__device__ __forceinline__ f32x4 mfma16(short8 a, short8 b, f32x4 c) {
  return __builtin_amdgcn_mfma_f32_16x16x32_bf16(a, b, c, 0, 0, 0);
}
__device__ __forceinline__ f32x16 mfma32(short8 a, short8 b, f32x16 c) {
  return __builtin_amdgcn_mfma_f32_32x32x16_bf16(a, b, c, 0, 0, 0);
}
__device__ __forceinline__ f32x16 zero16() {
  f32x16 z = {0.f,0.f,0.f,0.f,0.f,0.f,0.f,0.f,0.f,0.f,0.f,0.f,0.f,0.f,0.f,0.f};
  return z;
}

// ---------------- fp32 -> bf16 weight conversion ----------------
__global__ __launch_bounds__(256) void cvt_bf16_kernel(const float* __restrict__ in,
                                                       ushort* __restrict__ out, int n4) {
  int i = blockIdx.x * 256 + threadIdx.x;
  if (i < n4) {
    float4 v = reinterpret_cast<const float4*>(in)[i];
    ushort4 o; o.x = f2bf(v.x); o.y = f2bf(v.y); o.z = f2bf(v.z); o.w = f2bf(v.w);
    reinterpret_cast<ushort4*>(out)[i] = o;
  }
}

// ---------------- LayerNorm (fp32 in, bf16 out) ----------------
__global__ __launch_bounds__(256) void ln_kernel(const float* __restrict__ x,
                                                 const float* __restrict__ g,
                                                 const float* __restrict__ b,
                                                 ushort* __restrict__ out) {
  const int row = blockIdx.x, tid = threadIdx.x;
  const float4 xv = reinterpret_cast<const float4*>(x + (size_t)row * EMBED)[tid];
  float s  = xv.x + xv.y + xv.z + xv.w;
  float s2 = xv.x*xv.x + xv.y*xv.y + xv.z*xv.z + xv.w*xv.w;
  #pragma unroll
  for (int off = 32; off >= 1; off >>= 1) { s += __shfl_xor(s, off); s2 += __shfl_xor(s2, off); }
  __shared__ float ps[4], ps2[4];
  if ((tid & 63) == 0) { ps[tid >> 6] = s; ps2[tid >> 6] = s2; }
  __syncthreads();
  s  = ps[0] + ps[1] + ps[2] + ps[3];
  s2 = ps2[0] + ps2[1] + ps2[2] + ps2[3];
  const float mu  = s * (1.f / EMBED);
  const float var = s2 * (1.f / EMBED) - mu * mu;
  const float rs  = rsqrtf(var + 1e-5f);
  const float4 gv = reinterpret_cast<const float4*>(g)[tid];
  const float4 bv = reinterpret_cast<const float4*>(b)[tid];
  ushort4 o;
  o.x = f2bf((xv.x - mu) * rs * gv.x + bv.x);
  o.y = f2bf((xv.y - mu) * rs * gv.y + bv.y);
  o.z = f2bf((xv.z - mu) * rs * gv.z + bv.z);
  o.w = f2bf((xv.w - mu) * rs * gv.w + bv.w);
  reinterpret_cast<ushort4*>(out + (size_t)row * EMBED)[tid] = o;
}

// ---------------- bf16 GEMM: C[M,N] = A[M,K] * B[N,K]^T (+epilogue) ----------------
// SQ=true: 256x256 tile (8 waves 2Mx4N). SQ=false: 256x128 tile (8 waves 4Mx2N).
// Quad-buffered BK=32 tiles; stage tile u+3 during tile u; counted vmcnt; x4 unroll.
// L2-locality partition: XCD p owns contiguous M-slice (or N-slice if gx<8).
template<int EPI, bool SQ>
__global__ __launch_bounds__(512) void gemm256(const ushort* __restrict__ A,
                                               const ushort* __restrict__ B,
                                               const float* __restrict__ bias,
                                               const float* __restrict__ res,
                                               ushort* __restrict__ outb,
                                               float* __restrict__ outf,
                                               int M, int N, int K, int gx) {
  constexpr int BN   = SQ ? 256 : 128;
  constexpr int MP   = SQ ? 8 : 4;          // 16-row m-positions per wave
  constexpr int NPH  = SQ ? 2 : 1;          // phases per K-tile
  constexpr int LPT  = SQ ? 4 : 3;          // gload16 rounds per tile per thread
  constexpr int NB   = LPT - 2;             // B staging rounds
  constexpr int ABUF = 256 * 32;            // ushorts
  constexpr int BBUF = BN * 32;
  __shared__ ushort lds[4][ABUF + BBUF];

  const int nwg = gridDim.x;                // nwg % 8 == 0 for all our shapes
  const int b0  = blockIdx.x;
  // locality partition (XCD = blockIdx % 8)
  const int p = b0 & 7, li = b0 >> 3;
  int mt, nt;
  if ((gx & 7) == 0) {                      // partition M across XCDs
    const int g = gx >> 3;                  // m-tiles per XCD
    mt = p * g + (li % g);                  // m fastest within XCD
    nt = li / g;
  } else {                                  // partition N across XCDs (gy%8==0)
    const int g = (nwg / gx) >> 3;          // n-tiles per XCD
    nt = p * g + (li % g);                  // n fastest within XCD
    mt = li / g;
  }
  const int m0 = mt * 256;
  const int n0 = nt * BN;

  const int tid = threadIdx.x, lane = tid & 63, wave = tid >> 6;
  const int wm = (SQ ? (wave >> 2) : (wave >> 1)) * (MP * 16);
  const int wn = (SQ ? (wave & 3) : (wave & 1)) * 64;
  const int l15 = lane & 15, l4 = lane >> 4;
  const int NT = K >> 5;                    // divisible by 4 for all our shapes

  // per-thread staging source pointers; advance +32 elems per staged tile
  const ushort* aSrc[2];
  const ushort* bSrc[NB];
  #pragma unroll
  for (int rd = 0; rd < 2; ++rd) {
    const int slot = rd * 512 + tid;
    const int r = slot >> 2;
    const int cs = (slot & 3) ^ ((r >> 1) & 3);
    aSrc[rd] = A + (size_t)(m0 + r) * K + cs * 8;
  }
  #pragma unroll
  for (int rd = 0; rd < NB; ++rd) {
    const int slot = rd * 512 + tid;
    const int r = slot >> 2;
    const int cs = (slot & 3) ^ ((r >> 1) & 3);
    bSrc[rd] = B + (size_t)(n0 + r) * K + cs * 8;
  }
  auto stageA = [&](int buf, int rd) { gload16(aSrc[rd], &lds[buf][(rd * 512 + tid) * 8]); };
  auto stageB = [&](int buf, int rd) { gload16(bSrc[rd], &lds[buf][ABUF + (rd * 512 + tid) * 8]); };
  auto advance = [&]() {
    #pragma unroll
    for (int rd = 0; rd < 2; ++rd) aSrc[rd] += 32;
    #pragma unroll
    for (int rd = 0; rd < NB; ++rd) bSrc[rd] += 32;
  };

  // prologue: stage tiles 0..2 into bufs 0..2
  #pragma unroll
  for (int t = 0; t < 3; ++t) {
    stageA(t, 0); stageA(t, 1);
    #pragma unroll
    for (int rd = 0; rd < NB; ++rd) stageB(t, rd);
    advance();
  }
  vwait<2 * LPT>();               // tile 0 resident; 2 tiles stay in flight
  fence_bar();

  f32x4 acc[MP][4] = {};

  // one K-tile; q = buffer index (compile-time at every call site),
  // st = stage tile u+3, wsel: 0 -> vwait(2LPT), 1 -> vwait(LPT), 2 -> vwait(0), 3 -> none
  auto doTile = [&](int q, bool st, int wsel) {
    const ushort* bA = &lds[q][0];
    const ushort* bB = &lds[q][ABUF];
    const int sbuf = (q + 3) & 3;
    short8 bf[4];
    #pragma unroll
    for (int j = 0; j < 4; ++j) {
      const int rb = wn + j * 16 + l15;
      bf[j] = *reinterpret_cast<const short8*>(&bB[rb * 32 + ((l4 ^ ((rb >> 1) & 3)) * 8)]);
    }
    #pragma unroll
    for (int ph = 0; ph < NPH; ++ph) {
      short8 af[4];
      #pragma unroll
      for (int i = 0; i < 4; ++i) {
        const int ra = wm + (ph * 4 + i) * 16 + l15;
        af[i] = *reinterpret_cast<const short8*>(&bA[ra * 32 + ((l4 ^ ((ra >> 1) & 3)) * 8)]);
      }
      if (st) {
        if constexpr (SQ) {
          if (ph == 0) { stageA(sbuf, 0); stageA(sbuf, 1); }
          else         { stageB(sbuf, 0); stageB(sbuf, 1); }
        } else {
          stageA(sbuf, 0); stageA(sbuf, 1); stageB(sbuf, 0);
        }
      }
      fence_bar();
      __builtin_amdgcn_s_setprio(1);
      #pragma unroll
      for (int i = 0; i < 4; ++i)
        #pragma unroll
        for (int j = 0; j < 4; ++j)
          acc[ph * 4 + i][j] = mfma16(af[i], bf[j], acc[ph * 4 + i][j]);
      __builtin_amdgcn_s_setprio(0);
      if (ph == NPH - 1) {        // tile boundary: next tile must be resident
        if (st) advance();
        if (wsel == 0)      vwait<2 * LPT>();
        else if (wsel == 1) vwait<LPT>();
        else if (wsel == 2) vwait<0>();
      }
      fence_bar();
    }
  };

  for (int u0 = 0; u0 < NT - 4; u0 += 4) {
    doTile(0, true, 0); doTile(1, true, 0); doTile(2, true, 0); doTile(3, true, 0);
  }
  // tail: u = NT-4 .. NT-1
  doTile(0, true, 0); doTile(1, false, 1); doTile(2, false, 2); doTile(3, false, 3);

  #pragma unroll
  for (int i = 0; i < MP; ++i)
    #pragma unroll
    for (int j = 0; j < 4; ++j)
      #pragma unroll
      for (int r = 0; r < 4; ++r) {
        const int row = m0 + wm + i * 16 + l4 * 4 + r;
        const int col = n0 + wn + j * 16 + l15;
        const size_t idx = (size_t)row * N + col;
        float v = acc[i][j][r];
        if constexpr (EPI == 0) {
          outb[idx] = f2bf(v);
        } else if constexpr (EPI == 1) {
          outf[idx] = v + bias[col] + res[idx];
        } else {
          v += bias[col];
          v = 0.5f * v * (1.f + erff(v * 0.70710678118654752f));
          outb[idx] = f2bf(v);
        }
      }
}

// ---------------- flash attention, swapped-QK in-register softmax ----------------
// grid (B*H=64, SEQ/256=8), block 512 (8 waves). Wave: 32 q rows.
// qk: [8192][2048] bf16 (q at col h*64, k at col 1024+h*64). vt: [1024][8192] bf16.
// No 1/sqrt(d) scaling (per reference). 16 waves/CU for latency hiding.
#define KVB 64
#define NTT (SEQ / KVB)

__global__ __launch_bounds__(512, 4) void attn_kernel(const ushort* __restrict__ qk,
                                                      const ushort* __restrict__ vt,
                                                      ushort* __restrict__ outp) {
  const int tid = threadIdx.x, lane = tid & 63, wq = tid >> 6;   // wq 0..7
  const int hi = lane >> 5, lo = lane & 31;
  const int b = blockIdx.x >> 4, h = blockIdx.x & 15;
  const int q0 = blockIdx.y * 256;

  __shared__ ushort sK[2][64 * 64];
  __shared__ ushort sVt[2][64 * 64];
  __shared__ float sBc[8][32];

  // Q fragments (B-operand): wave covers q rows q0 + wq*32 .. +31 (lane q = lo)
  short8 qf[4];
  #pragma unroll
  for (int kc = 0; kc < 4; ++kc)
    qf[kc] = *reinterpret_cast<const short8*>(
        qk + (size_t)(b * SEQ + q0 + wq * 32 + lo) * 2048 + h * 64 + kc * 16 + hi * 8);

  auto STAGE = [&](int bb, int kt) {
    const int r = tid >> 3;
    const int c = (tid & 7) ^ (r & 7);            // inverse-swizzled source chunk
    gload16(qk + (size_t)(b * SEQ + kt + r) * 2048 + 1024 + h * 64 + c * 8,
            &sK[bb][wq * 64 * 8]);                // wave-uniform dest + lane*16B
    gload16(vt + (size_t)(h * 64 + r) * 8192 + b * SEQ + kt + c * 8,
            &sVt[bb][wq * 64 * 8]);
  };

  f32x16 acc[2];
  acc[0] = zero16(); acc[1] = zero16();
  float mst = -1e30f, lst = 0.f;

  STAGE(0, 0);
  for (int t = 0; t < NTT; ++t) {
    const int cur = t & 1;
    __syncthreads();                       // staged buf[cur] ready; buf[cur^1] free
    if (t + 1 < NTT) STAGE(cur ^ 1, (t + 1) * KVB);

    // K fragments (A-operand): row kv, swizzled b128 reads
    short8 kf[2][4];
    #pragma unroll
    for (int kvb = 0; kvb < 2; ++kvb)
      #pragma unroll
      for (int kc = 0; kc < 4; ++kc) {
        const int row = kvb * 32 + lo, ch = kc * 2 + hi;
        kf[kvb][kc] = *reinterpret_cast<const short8*>(
            &sK[cur][(row * 8 + (ch ^ (row & 7))) * 8]);
      }

    // S^T = K * Q^T : lane holds q=lo, kv rows in regs
    f32x16 st[2];
    #pragma unroll
    for (int kvb = 0; kvb < 2; ++kvb) {
      f32x16 tq = zero16();
      tq = mfma32(kf[kvb][0], qf[0], tq);
      tq = mfma32(kf[kvb][1], qf[1], tq);
      tq = mfma32(kf[kvb][2], qf[2], tq);
      tq = mfma32(kf[kvb][3], qf[3], tq);
      st[kvb] = tq;
    }
    // row max: in-register tree + one cross-half swap
    float pm = fmaxf(st[0][0], st[0][1]);
    #pragma unroll
    for (int r = 2; r < 16; ++r) pm = fmaxf(pm, st[0][r]);
    #pragma unroll
    for (int r = 0; r < 16; ++r) pm = fmaxf(pm, st[1][r]);
    pm = fmaxf(pm, __shfl_xor(pm, 32));
    // defer-max: rescale only when max grew by > 8
    if (__any(pm > mst + 8.f)) {
      const float mn = fmaxf(mst, pm);
      const float al = __expf(mst - mn);
      mst = mn; lst *= al;
      sBc[wq][lo] = al;
      lgkm0();
      #pragma unroll
      for (int g = 0; g < 4; ++g) {
        const f32x4 a4 = *reinterpret_cast<const f32x4*>(&sBc[wq][g * 8 + hi * 4]);
        #pragma unroll
        for (int j = 0; j < 4; ++j) {
          acc[0][g * 4 + j] *= a4[j];
          acc[1][g * 4 + j] *= a4[j];
        }
      }
    }
    // P = exp(S - m), row sum
    #pragma unroll
    for (int kvb = 0; kvb < 2; ++kvb)
      #pragma unroll
      for (int r = 0; r < 16; ++r)
        st[kvb][r] = __expf(st[kvb][r] - mst);
    {
      const f32x16 sv = st[0] + st[1];
      float sum = ((sv[0] + sv[1]) + (sv[2] + sv[3])) + ((sv[4] + sv[5]) + (sv[6] + sv[7]))
                + ((sv[8] + sv[9]) + (sv[10] + sv[11])) + ((sv[12] + sv[13]) + (sv[14] + sv[15]));
      sum += __shfl_xor(sum, 32);
      lst += sum;
    }
    // pack P -> bf16 A-fragments via cvt_pk + permlane32_swap
    short8 pa[4];
    #pragma unroll
    for (int kvb = 0; kvb < 2; ++kvb)
      #pragma unroll
      for (int f = 0; f < 2; ++f) {
        uint32_t wa = pkbf(st[kvb][f * 8 + 0], st[kvb][f * 8 + 1]);
        uint32_t wb = pkbf(st[kvb][f * 8 + 2], st[kvb][f * 8 + 3]);
        uint32_t wc = pkbf(st[kvb][f * 8 + 4], st[kvb][f * 8 + 5]);
        uint32_t wd = pkbf(st[kvb][f * 8 + 6], st[kvb][f * 8 + 7]);
        asm volatile("v_permlane32_swap_b32 %0, %1" : "+v"(wa), "+v"(wc));
        asm volatile("v_permlane32_swap_b32 %0, %1" : "+v"(wb), "+v"(wd));
        union { uint32_t w[4]; short8 v; } u;
        u.w[0] = wa; u.w[1] = wb; u.w[2] = wc; u.w[3] = wd;
        pa[kvb * 2 + f] = u.v;
      }

    // O += P V  (B-operand = V^T rows d)
    #pragma unroll
    for (int db = 0; db < 2; ++db) {
      short8 vb[4];
      #pragma unroll
      for (int k4 = 0; k4 < 4; ++k4) {
        const int row = db * 32 + lo, ch = k4 * 2 + hi;
        vb[k4] = *reinterpret_cast<const short8*>(
            &sVt[cur][(row * 8 + (ch ^ (row & 7))) * 8]);
      }
      acc[db] = mfma32(pa[0], vb[0], acc[db]);
      acc[db] = mfma32(pa[1], vb[1], acc[db]);
      acc[db] = mfma32(pa[2], vb[2], acc[db]);
      acc[db] = mfma32(pa[3], vb[3], acc[db]);
    }
  }

  // epilogue: O /= l, write bf16 [8192][1024]
  sBc[wq][lo] = 1.f / lst;
  lgkm0();
  #pragma unroll
  for (int g = 0; g < 4; ++g) {
    const f32x4 r4 = *reinterpret_cast<const f32x4*>(&sBc[wq][g * 8 + hi * 4]);
    #pragma unroll
    for (int j = 0; j < 4; ++j) {
      const int qrow = q0 + wq * 32 + g * 8 + hi * 4 + j;
      #pragma unroll
      for (int db = 0; db < 2; ++db)
        outp[(size_t)(b * SEQ + qrow) * EMBED + h * 64 + db * 32 + lo] =
            f2bf(acc[db][g * 4 + j] * r4[j]);
    }
  }
}

// ---------------- launch ----------------
extern "C" void kernel_launch(void* const* d_in, const int* in_sizes, int n_in,
                              void* d_out, int out_size, void* d_ws, size_t ws_size,
                              hipStream_t stream) {
  const float* x     = (const float*)d_in[0];
  const float* ln1_g = (const float*)d_in[1];
  const float* ln1_b = (const float*)d_in[2];
  const float* qkv_w = (const float*)d_in[3];
  const float* out_w = (const float*)d_in[4];
  const float* out_b = (const float*)d_in[5];
  const float* ln2_g = (const float*)d_in[6];
  const float* ln2_b = (const float*)d_in[7];
  const float* fc1_w = (const float*)d_in[8];
  const float* fc1_b = (const float*)d_in[9];
  const float* fc2_w = (const float*)d_in[10];
  const float* fc2_b = (const float*)d_in[11];
  float* out = (float*)d_out;
  char* ws = (char*)d_ws;

  // workspace layout (bytes)
  ushort* qkvw = (ushort*)(ws);                                   //  6291456
  ushort* outw = (ushort*)(ws + 6291456);                         //  2097152
  ushort* fc1w = (ushort*)(ws + 8388608);                         //  8388608
  ushort* fc2w = (ushort*)(ws + 16777216);                        //  8388608
  float*  x1   = (float*) (ws + 25165824);                        // 33554432
  ushort* hbuf = (ushort*)(ws + 58720256);                        // 16777216
  ushort* qkbuf= (ushort*)(ws + 75497472);                        // 33554432  [8192][2048]
  ushort* vtbuf= (ushort*)(ws + 109051904);                       // 16777216  [1024][8192]
  ushort* obuf = (ushort*)(ws + 125829120);                       // 16777216
  ushort* gbuf = qkbuf;  // gelu buf [8192][4096] reuses qk+vt+o regions (64 MiB)

  cvt_bf16_kernel<<<3072, 256, 0, stream>>>(qkv_w, qkvw, 3 * EMBED * EMBED / 4);
  cvt_bf16_kernel<<<1024, 256, 0, stream>>>(out_w, outw, EMBED * EMBED / 4);
  cvt_bf16_kernel<<<4096, 256, 0, stream>>>(fc1_w, fc1w, HIDDEN * EMBED / 4);
  cvt_bf16_kernel<<<4096, 256, 0, stream>>>(fc2_w, fc2w, EMBED * HIDDEN / 4);

  ln_kernel<<<NTOK, 256, 0, stream>>>(x, ln1_g, ln1_b, hbuf);
  // QK: [8192][2048] = hbuf * Wqk^T   (256x256 tiles, M-partitioned)
  gemm256<0, true><<<256, 512, 0, stream>>>(hbuf, qkvw, nullptr, nullptr,
                                            qkbuf, nullptr, NTOK, 2 * EMBED, EMBED, 32);
  // V^T: [1024][8192] = Wv * hbuf^T   (256x128 tiles, N-partitioned)
  gemm256<0, false><<<256, 512, 0, stream>>>(qkvw + 2048 * 1024, hbuf, nullptr, nullptr,
                                             vtbuf, nullptr, EMBED, NTOK, EMBED, 4);
  attn_kernel<<<dim3(64, 8), 512, 0, stream>>>(qkbuf, vtbuf, obuf);
  // out-proj
  gemm256<1, false><<<256, 512, 0, stream>>>(obuf, outw, out_b, x,
                                             nullptr, x1, NTOK, EMBED, EMBED, 32);
  ln_kernel<<<NTOK, 256, 0, stream>>>(x1, ln2_g, ln2_b, hbuf);
  // fc1
  gemm256<2, true><<<512, 512, 0, stream>>>(hbuf, fc1w, fc1_b, nullptr,
                                            gbuf, nullptr, NTOK, HIDDEN, EMBED, 32);
  // fc2
  gemm256<1, false><<<256, 512, 0, stream>>>(gbuf, fc2w, fc2_b, x1,
                                             nullptr, out, NTOK, EMBED, HIDDEN, 32);
}